// Round 11
// baseline (217.104 us; speedup 1.0000x reference)
//
#include <hip/hip_runtime.h>

#define C_DIM 384
#define S_DIM 196
#define CS_   (C_DIM * S_DIM)      // 75264
#define BCS   (32 * CS_)           // 2408448 elements per t-slab (B*C*S)
#define NELEM (128 * CS_)          // 9633792 total per tensor
#define NBS   6272                 // 32 * 196 (b,s) pairs

typedef _Float16 half8  __attribute__((ext_vector_type(8)));
typedef float    floatx4 __attribute__((ext_vector_type(4)));

// async 16B/lane global->LDS copy; LDS base wave-uniform, HW adds lane*16.
__device__ __forceinline__ void gl_lds16(const _Float16* g, _Float16* l) {
    __builtin_amdgcn_global_load_lds(
        (const __attribute__((address_space(1))) unsigned int*)g,
        (__attribute__((address_space(3))) unsigned int*)l, 16, 0, 0);
}

// ---------------------------------------------------------------------------
// prep: [bid < 768] split+transpose X -> X0/X1 [m'=(b*196+s)*4+t][c] fp16,
//       64-channel blocks so every 2B-element row chunk is a full 128 B line;
//       [bid >= 768] split weights into fp16 hi/lo(x4096) planes + BN consts.
// ---------------------------------------------------------------------------
__global__ __launch_bounds__(256)
void prep(const float* __restrict__ X,
          const float* __restrict__ qw, const float* __restrict__ kw,
          const float* __restrict__ pw,
          const float* qg, const float* qb, const float* qm, const float* qv,
          const float* kg, const float* kb, const float* km, const float* kv,
          const float* pg, const float* pb, const float* pm, const float* pv,
          _Float16* __restrict__ X0, _Float16* __restrict__ X1,
          _Float16* __restrict__ Wq0, _Float16* __restrict__ Wq1,
          _Float16* __restrict__ Wp0, _Float16* __restrict__ Wp1,
          float2* __restrict__ invshQ, float2* __restrict__ invshP)
{
    __shared__ float tile[64][201];     // 51.5 KB
    const int bid = blockIdx.x;
    const int t   = threadIdx.x;
    if (bid < 768) {
        const int tb = bid / 6, cch = bid % 6;
        const int tt = tb >> 5, b = tb & 31;
        const int c0 = cch * 64;
        for (int idx = t; idx < 64 * S_DIM; idx += 256) {
            const int cc = idx / S_DIM, s = idx - cc * S_DIM;
            tile[cc][s] = X[(size_t)tb * CS_ + (c0 + cc) * S_DIM + s];
        }
        __syncthreads();
        for (int idx = t; idx < 64 * S_DIM; idx += 256) {
            const int s = idx >> 6, cc = idx & 63;   // cc fastest: 128 B lines
            const float v = tile[cc][s];
            const _Float16 h0 = (_Float16)v;
            const size_t off = ((size_t)(b * S_DIM + s) * 4 + tt) * C_DIM + c0 + cc;
            X0[off] = h0;
            X1[off] = (_Float16)((v - (float)h0) * 4096.0f);
        }
    } else {
        const int i = (bid - 768) * 256 + t;
        const int NQ = 768 * C_DIM;
        if (i < NQ) {
            const int o = i / C_DIM, c = i - o * C_DIM;
            const float v = (o < 384) ? qw[o * C_DIM + c] : kw[(o - 384) * C_DIM + c];
            const _Float16 h0 = (_Float16)v;
            Wq0[i] = h0;
            Wq1[i] = (_Float16)((v - (float)h0) * 4096.0f);
        } else if (i < NQ + C_DIM * C_DIM) {
            const int j = i - NQ;
            const float v = pw[j];
            const _Float16 h0 = (_Float16)v;
            Wp0[j] = h0;
            Wp1[j] = (_Float16)((v - (float)h0) * 4096.0f);
        }
        if (i < 768) {
            float g, b2, m, vv;
            if (i < 384) { g = qg[i]; b2 = qb[i]; m = qm[i]; vv = qv[i]; }
            else         { g = kg[i-384]; b2 = kb[i-384]; m = km[i-384]; vv = kv[i-384]; }
            const float inv = g / sqrtf(vv + 1e-5f);
            invshQ[i] = make_float2(inv, b2 - m * inv);
        } else if (i < 1152) {
            const int j = i - 768;
            const float inv = pg[j] / sqrtf(pv[j] + 1e-5f);
            invshP[j] = make_float2(inv, pb[j] - pm[j] * inv);
        }
    }
}

// ---------------------------------------------------------------------------
// Fused-split qk GEMM + BN + IN-LANE LIF -> spike bytes [bs][c].
// BARRIER-FREE wave-private staging: each wave stages (glds) exactly the
// 64 o-rows and 64 m-rows it reads; vmcnt is per-wave, so no __syncthreads
// anywhere -- waves anti-phase staging vs MFMA across the CU.
// acc += X0*W1 + X1*W0 + (4096*X0)*W0; x = acc*2^-12*inv+sh.
// ---------------------------------------------------------------------------
__global__ __launch_bounds__(256, 2)
void qk_mfma(const _Float16* __restrict__ A0, const _Float16* __restrict__ A1,
             const _Float16* __restrict__ B0, const _Float16* __restrict__ B1,
             const float2* __restrict__ invsh,
             unsigned char* __restrict__ spkQ, unsigned char* __restrict__ spkK)
{
    __shared__ __align__(16) _Float16 lds[32768];   // 64 KB: 4 waves x 16 KB

    const int t    = threadIdx.x;
    const int wave = t >> 6, lane = t & 63;
    const int m0 = blockIdx.x * 128;   // m fastest (known-good order)
    const int o0 = blockIdx.y * 128;

    const int lo = lane & 15, quad = lane >> 4;
    const int oq = (wave >> 1) * 64, mq = (wave & 1) * 64;

    _Float16* As0 = lds + wave * 8192;    // W0: 64 rows x 32
    _Float16* As1 = As0 + 2048;           // W1
    _Float16* Bs0 = As0 + 4096;           // X0
    _Float16* Bs1 = As0 + 6144;           // X1

    const int sRow = lane >> 2;                                  // 0..15
    const int sC   = ((lane & 3) ^ ((sRow >> 1) & 3)) << 3;      // src swizzle
    const int rdC  = (quad ^ ((lo >> 1) & 3)) << 3;              // un-swizzle

    floatx4 acc[4][4];   // [i = m-frag][j = o-frag]
    #pragma unroll
    for (int i = 0; i < 4; ++i)
        #pragma unroll
        for (int j = 0; j < 4; ++j) acc[i][j] = (floatx4)0.0f;

    for (int kt = 0; kt < 12; ++kt) {
        const int kb = kt * 32;
        #pragma unroll
        for (int g = 0; g < 4; ++g) {    // 4 groups of 16 rows = 64 rows
            const int R = g * 16;
            const size_t ga = (size_t)(o0 + oq + R + sRow) * C_DIM + kb + sC;
            const size_t gb = (size_t)(m0 + mq + R + sRow) * C_DIM + kb + sC;
            gl_lds16(A0 + ga, &As0[R * 32]);
            gl_lds16(A1 + ga, &As1[R * 32]);
            gl_lds16(B0 + gb, &Bs0[R * 32]);
            gl_lds16(B1 + gb, &Bs1[R * 32]);
        }
        // no barrier: this wave reads only what it staged; compiler orders
        // glds -> ds_read via vmcnt, ds_read -> next glds via lgkmcnt.

        half8 w0F[4], w1F[4], x0F[4], x1F[4];
        #pragma unroll
        for (int j = 0; j < 4; ++j) {
            const int ra = (j * 16 + lo) * 32 + rdC;
            w0F[j] = *(const half8*)&As0[ra];
            w1F[j] = *(const half8*)&As1[ra];
        }
        #pragma unroll
        for (int i = 0; i < 4; ++i) {
            const int rb = (i * 16 + lo) * 32 + rdC;
            x0F[i] = *(const half8*)&Bs0[rb];
            x1F[i] = *(const half8*)&Bs1[rb];
        }
        #pragma unroll
        for (int i = 0; i < 4; ++i) {
            const half8 xS = x0F[i] * (_Float16)4096.0f;   // exact pow2 scale
            #pragma unroll
            for (int j = 0; j < 4; ++j) {
                acc[i][j] = __builtin_amdgcn_mfma_f32_16x16x32_f16(
                    x0F[i], w1F[j], acc[i][j], 0, 0, 0);
                acc[i][j] = __builtin_amdgcn_mfma_f32_16x16x32_f16(
                    x1F[i], w0F[j], acc[i][j], 0, 0, 0);
                acc[i][j] = __builtin_amdgcn_mfma_f32_16x16x32_f16(
                    xS,     w0F[j], acc[i][j], 0, 0, 0);
            }
        }
    }

    // epilogue: D rows = m' (quad picks bs, reg picks t), cols = o.
    #pragma unroll
    for (int j = 0; j < 4; ++j) {
        const int o = o0 + oq + j * 16 + lo;
        const float2 is = invsh[o];
        const float inv = is.x * (1.0f / 4096.0f);
        const float sh  = is.y;
        unsigned char* base = (o < 384) ? spkQ : spkK;
        const int orow = (o < 384) ? o : o - 384;
        #pragma unroll
        for (int i = 0; i < 4; ++i) {
            const int bs = ((m0 + mq + i * 16) >> 2) + quad;
            float v = 0.0f; int bits = 0;
            #pragma unroll
            for (int r = 0; r < 4; ++r) {
                const float xv = acc[i][j][r] * inv + sh;
                const float h = v + (xv - v) * 0.5f;
                const int sp = (h >= 1.0f);
                v = sp ? 0.0f : h;
                bits |= sp << r;
            }
            base[(size_t)bs * C_DIM + orow] = (unsigned char)bits;
        }
    }
}

// ---------------------------------------------------------------------------
// Fused-split proj GEMM with per-block attn recompute (grid m-fastest).
// Y (binary) = A-operand, W planes = B-operand. acc += Y*W1 + Y*(4096*W0).
// Epilogue: in-lane LIF -> per-t LDS transpose -> coalesced float4 stores.
// ---------------------------------------------------------------------------
__global__ __launch_bounds__(256, 3)
void proj_mfma(const _Float16* __restrict__ A0, const _Float16* __restrict__ A1,
               const unsigned char* __restrict__ spkQ,
               const unsigned char* __restrict__ spkK,
               const float* __restrict__ bias, const float2* __restrict__ invsh,
               float* __restrict__ out)
{
    __shared__ __align__(16) _Float16 smem[3 * 128 * 32];   // 24 KB
    __shared__ unsigned char attnL[256];                     // 32 bs x 8 heads
    _Float16* As0 = smem;                 // W0 (o rows)
    _Float16* As1 = smem + 4096;          // W1
    _Float16* Bs0 = smem + 8192;          // Y  (m' rows)

    const int t    = threadIdx.x;
    const int wave = t >> 6, lane = t & 63;
    const int m0 = blockIdx.x * 128;
    const int o0 = blockIdx.y * 128;

    const int wR   = wave * 32;
    const int sRow = lane >> 2;
    const int sCol = (((lane & 3) ^ ((sRow >> 1) & 3))) << 3;   // A glds swizzle
    const int gC8  = (lane & 3) << 3;                            // B global chunk
    const int pC8  = sCol;                                       // B LDS swizzle

    const int lo = lane & 15, quad = lane >> 4;
    const int oq = (wave >> 1) * 64, mq = (wave & 1) * 64;
    const int rdC = (quad ^ ((lo >> 1) & 3)) << 3;

    const int bs0g   = m0 >> 2;
    const int bsl[2] = { (wR +  0 + sRow) >> 2, (wR + 16 + sRow) >> 2 }; // local
    const int ttL    = (wR + sRow) & 3;

    // --- per-block attn recompute (exact dyadic) ---
    {
        const int bsl_a = t >> 3, head = t & 7;
        const unsigned long long* p = (const unsigned long long*)
            (spkQ + (size_t)(bs0g + bsl_a) * C_DIM + head * 48);
        int qs[4] = {0, 0, 0, 0};
        #pragma unroll
        for (int u = 0; u < 6; ++u) {
            const unsigned long long v = p[u];
            qs[0] += __popcll(v & 0x0101010101010101ull);
            qs[1] += __popcll(v & 0x0202020202020202ull);
            qs[2] += __popcll(v & 0x0404040404040404ull);
            qs[3] += __popcll(v & 0x0808080808080808ull);
        }
        float va = 0.0f; int bits = 0;
        #pragma unroll
        for (int tt = 0; tt < 4; ++tt) {
            const float h = va + ((float)qs[tt] - va) * 0.5f;
            const int a = (h >= 0.5f);
            va = a ? 0.0f : h;
            bits |= a << tt;
        }
        attnL[t] = (unsigned char)bits;
    }
    __syncthreads();

    floatx4 acc[4][4];   // [i = m-frag][j = o-frag]
    #pragma unroll
    for (int i = 0; i < 4; ++i)
        #pragma unroll
        for (int j = 0; j < 4; ++j) acc[i][j] = (floatx4)0.0f;

    unsigned long long rk[2];
    int rab[2];
    {
        const int head0 = gC8 / 48;
        #pragma unroll
        for (int u = 0; u < 2; ++u) {
            rk[u]  = *(const unsigned long long*)
                     (spkK + (size_t)(bs0g + bsl[u]) * C_DIM + gC8);
            rab[u] = (attnL[bsl[u] * 8 + head0] >> ttL) & 1;
        }
    }

    for (int kt = 0; kt < 12; ++kt) {
        __syncthreads();
        const int kb = kt * 32;
        #pragma unroll
        for (int u = 0; u < 2; ++u) {
            const int R = wR + u * 16;
            half8 bv;
            #pragma unroll
            for (int e = 0; e < 8; ++e)
                bv[e] = (_Float16)(float)((int)(rk[u] >> (8 * e + ttL)) & rab[u] & 1);
            *(half8*)&Bs0[(R + sRow) * 32 + pC8] = bv;
            const size_t ga = (size_t)(o0 + R + sRow) * C_DIM + kb + sCol;
            gl_lds16(A0 + ga, &As0[R * 32]);
            gl_lds16(A1 + ga, &As1[R * 32]);
        }
        if (kt < 11) {
            const int kb2  = (kt + 1) * 32;
            const int head = (kb2 + gC8) / 48;
            #pragma unroll
            for (int u = 0; u < 2; ++u) {
                rk[u]  = *(const unsigned long long*)
                         (spkK + (size_t)(bs0g + bsl[u]) * C_DIM + kb2 + gC8);
                rab[u] = (attnL[bsl[u] * 8 + head] >> ttL) & 1;
            }
        }
        __syncthreads();

        half8 w0F[4], w1F[4], yF[4];
        #pragma unroll
        for (int j = 0; j < 4; ++j) {
            const int ra = (oq + j * 16 + lo) * 32 + rdC;
            w0F[j] = *(const half8*)&As0[ra];
            w1F[j] = *(const half8*)&As1[ra];
        }
        #pragma unroll
        for (int i = 0; i < 4; ++i)
            yF[i] = *(const half8*)&Bs0[(mq + i * 16 + lo) * 32 + rdC];

        #pragma unroll
        for (int j = 0; j < 4; ++j) {
            const half8 wS = w0F[j] * (_Float16)4096.0f;
            #pragma unroll
            for (int i = 0; i < 4; ++i) {
                acc[i][j] = __builtin_amdgcn_mfma_f32_16x16x32_f16(
                    yF[i], w1F[j], acc[i][j], 0, 0, 0);
                acc[i][j] = __builtin_amdgcn_mfma_f32_16x16x32_f16(
                    yF[i], wS,     acc[i][j], 0, 0, 0);
            }
        }
    }

    // in-lane LIF -> 4 spike bits per (i,j)
    int bits[4][4];
    #pragma unroll
    for (int j = 0; j < 4; ++j) {
        const int o = o0 + oq + j * 16 + lo;
        const float2 is = invsh[o];
        const float bv = bias[o];
        #pragma unroll
        for (int i = 0; i < 4; ++i) {
            float v = 0.0f; int bt = 0;
            #pragma unroll
            for (int r = 0; r < 4; ++r) {
                const float p = acc[i][j][r] * (1.0f / 4096.0f);
                const float z = (p + bv) * is.x + is.y;
                const float h = v + (z - v) * 0.5f;
                const int sp = (h >= 1.0f);
                v = sp ? 0.0f : h;
                bt |= sp << r;
            }
            bits[i][j] = bt;
        }
    }

    // per-t: LDS transpose (128 o x 32 bs, pad 33) + coalesced float4 stores
    float* tile = (float*)smem;            // 16.9 KB
    for (int r = 0; r < 4; ++r) {
        __syncthreads();
        #pragma unroll
        for (int j = 0; j < 4; ++j)
            #pragma unroll
            for (int i = 0; i < 4; ++i)
                tile[(oq + j * 16 + lo) * 33 + (mq >> 2) + i * 4 + quad] =
                    ((bits[i][j] >> r) & 1) ? 1.0f : 0.0f;
        __syncthreads();
        #pragma unroll
        for (int it = 0; it < 4; ++it) {
            const int idx = it * 256 + t;        // 0..1023
            const int o   = idx >> 3;
            const int ch  = idx & 7;
            const int bsg = bs0g + ch * 4;       // 4-chunk never straddles b
            const int b   = bsg / S_DIM;
            const int s   = bsg - b * S_DIM;
            float4 vv;
            vv.x = tile[o * 33 + ch * 4 + 0];
            vv.y = tile[o * 33 + ch * 4 + 1];
            vv.z = tile[o * 33 + ch * 4 + 2];
            vv.w = tile[o * 33 + ch * 4 + 3];
            *(float4*)(out + (size_t)r * BCS + (size_t)b * CS_
                           + (size_t)(o0 + o) * S_DIM + s) = vv;
        }
    }
}

// ---------------------------------------------------------------------------
extern "C" void kernel_launch(void* const* d_in, const int* in_sizes, int n_in,
                              void* d_out, int out_size, void* d_ws, size_t ws_size,
                              hipStream_t stream)
{
    const float* x          = (const float*)d_in[0];
    const float* q_w        = (const float*)d_in[1];
    const float* q_gamma    = (const float*)d_in[2];
    const float* q_beta     = (const float*)d_in[3];
    const float* q_mean     = (const float*)d_in[4];
    const float* q_var      = (const float*)d_in[5];
    const float* k_w        = (const float*)d_in[6];
    const float* k_gamma    = (const float*)d_in[7];
    const float* k_beta     = (const float*)d_in[8];
    const float* k_mean     = (const float*)d_in[9];
    const float* k_var      = (const float*)d_in[10];
    const float* proj_w     = (const float*)d_in[11];
    const float* proj_b     = (const float*)d_in[12];
    const float* proj_gamma = (const float*)d_in[13];
    const float* proj_beta  = (const float*)d_in[14];
    const float* proj_mean  = (const float*)d_in[15];
    const float* proj_var   = (const float*)d_in[16];
    float* out = (float*)d_out;

    _Float16* h0 = (_Float16*)d_ws;         // X0 (b,s,t)-major
    _Float16* h1 = h0 + NELEM;              // X1
    _Float16* Wq0 = h1 + NELEM;             // 768x384
    _Float16* Wq1 = Wq0 + 768 * C_DIM;
    _Float16* Wp0 = Wq1 + 768 * C_DIM;      // 384x384
    _Float16* Wp1 = Wp0 + C_DIM * C_DIM;
    float2*   invshQ = (float2*)(Wp1 + C_DIM * C_DIM);   // 768 (q|k)
    float2*   invshP = invshQ + 768;                     // 384 (proj)
    unsigned char* spkQ  = (unsigned char*)(invshP + 384);  // NBS*384
    unsigned char* spkK  = spkQ + (size_t)NBS * C_DIM;

    prep<<<2496, 256, 0, stream>>>(x, q_w, k_w, proj_w,
                                   q_gamma, q_beta, q_mean, q_var,
                                   k_gamma, k_beta, k_mean, k_var,
                                   proj_gamma, proj_beta, proj_mean, proj_var,
                                   h0, h1, Wq0, Wq1, Wp0, Wp1, invshQ, invshP);

    qk_mfma<<<dim3(196, 6), 256, 0, stream>>>(Wq0, Wq1, h0, h1, invshQ,
                                              spkQ, spkK);
    proj_mfma<<<dim3(196, 3), 256, 0, stream>>>(Wp0, Wp1, spkQ, spkK,
                                                proj_b, invshP, out);
}

// Round 12
// 194.846 us; speedup vs baseline: 1.1142x; 1.1142x over previous
//
#include <hip/hip_runtime.h>

#define C_DIM 384
#define S_DIM 196
#define CS_   (C_DIM * S_DIM)      // 75264
#define BCS   (32 * CS_)           // 2408448 elements per t-slab (B*C*S)
#define NELEM (128 * CS_)          // 9633792 total per tensor
#define NBS   6272                 // 32 * 196 (b,s) pairs

typedef _Float16 half8  __attribute__((ext_vector_type(8)));
typedef float    floatx4 __attribute__((ext_vector_type(4)));

// async 16B/lane global->LDS copy; LDS base wave-uniform, HW adds lane*16.
__device__ __forceinline__ void gl_lds16(const _Float16* g, _Float16* l) {
    __builtin_amdgcn_global_load_lds(
        (const __attribute__((address_space(1))) unsigned int*)g,
        (__attribute__((address_space(3))) unsigned int*)l, 16, 0, 0);
}

// ---------------------------------------------------------------------------
// prep: [bid < 768] split+transpose X -> X0/X1 [m'=(b*196+s)*4+t][c] fp16,
//       64-channel blocks so each c-row chunk is a full 128 B line;
//       [bid >= 768] split weights into fp16 hi/lo(x4096) planes + BN consts.
// ---------------------------------------------------------------------------
__global__ __launch_bounds__(256)
void prep(const float* __restrict__ X,
          const float* __restrict__ qw, const float* __restrict__ kw,
          const float* __restrict__ pw,
          const float* qg, const float* qb, const float* qm, const float* qv,
          const float* kg, const float* kb, const float* km, const float* kv,
          const float* pg, const float* pb, const float* pm, const float* pv,
          _Float16* __restrict__ X0, _Float16* __restrict__ X1,
          _Float16* __restrict__ Wq0, _Float16* __restrict__ Wq1,
          _Float16* __restrict__ Wp0, _Float16* __restrict__ Wp1,
          float2* __restrict__ invshQ, float2* __restrict__ invshP)
{
    __shared__ float tile[64][201];     // 51.5 KB
    const int bid = blockIdx.x;
    const int t   = threadIdx.x;
    if (bid < 768) {
        const int tb = bid / 6, cch = bid % 6;
        const int tt = tb >> 5, b = tb & 31;
        const int c0 = cch * 64;
        for (int idx = t; idx < 64 * S_DIM; idx += 256) {
            const int cc = idx / S_DIM, s = idx - cc * S_DIM;
            tile[cc][s] = X[(size_t)tb * CS_ + (c0 + cc) * S_DIM + s];
        }
        __syncthreads();
        for (int idx = t; idx < 64 * S_DIM; idx += 256) {
            const int s = idx >> 6, cc = idx & 63;   // cc fastest: 128 B lines
            const float v = tile[cc][s];
            const _Float16 h0 = (_Float16)v;
            const size_t off = ((size_t)(b * S_DIM + s) * 4 + tt) * C_DIM + c0 + cc;
            X0[off] = h0;
            X1[off] = (_Float16)((v - (float)h0) * 4096.0f);
        }
    } else {
        const int i = (bid - 768) * 256 + t;
        const int NQ = 768 * C_DIM;
        if (i < NQ) {
            const int o = i / C_DIM, c = i - o * C_DIM;
            const float v = (o < 384) ? qw[o * C_DIM + c] : kw[(o - 384) * C_DIM + c];
            const _Float16 h0 = (_Float16)v;
            Wq0[i] = h0;
            Wq1[i] = (_Float16)((v - (float)h0) * 4096.0f);
        } else if (i < NQ + C_DIM * C_DIM) {
            const int j = i - NQ;
            const float v = pw[j];
            const _Float16 h0 = (_Float16)v;
            Wp0[j] = h0;
            Wp1[j] = (_Float16)((v - (float)h0) * 4096.0f);
        }
        if (i < 768) {
            float g, b2, m, vv;
            if (i < 384) { g = qg[i]; b2 = qb[i]; m = qm[i]; vv = qv[i]; }
            else         { g = kg[i-384]; b2 = kb[i-384]; m = km[i-384]; vv = kv[i-384]; }
            const float inv = g / sqrtf(vv + 1e-5f);
            invshQ[i] = make_float2(inv, b2 - m * inv);
        } else if (i < 1152) {
            const int j = i - 768;
            const float inv = pg[j] / sqrtf(pv[j] + 1e-5f);
            invshP[j] = make_float2(inv, pb[j] - pm[j] * inv);
        }
    }
}

// ---------------------------------------------------------------------------
// Fused-split qk GEMM + BN + IN-LANE LIF -> spike bytes [bs][c].
// Round-9 structure (measured 55 us): barrier glds staging, 32 KB LDS,
// 3 blocks/CU, grid m-fastest.
// acc += X0*W1 + X1*W0 + (4096*X0)*W0; x = acc*2^-12*inv+sh.
// ---------------------------------------------------------------------------
__global__ __launch_bounds__(256, 3)
void qk_mfma(const _Float16* __restrict__ A0, const _Float16* __restrict__ A1,
             const _Float16* __restrict__ B0, const _Float16* __restrict__ B1,
             const float2* __restrict__ invsh,
             unsigned char* __restrict__ spkQ, unsigned char* __restrict__ spkK)
{
    __shared__ __align__(16) _Float16 As0[128 * 32];   // W0 tile (o rows)
    __shared__ __align__(16) _Float16 As1[128 * 32];   // W1 tile
    __shared__ __align__(16) _Float16 Bs0[128 * 32];   // X0 tile (m' rows)
    __shared__ __align__(16) _Float16 Bs1[128 * 32];   // X1 tile

    const int t    = threadIdx.x;
    const int wave = t >> 6, lane = t & 63;
    const int m0 = blockIdx.x * 128;
    const int o0 = blockIdx.y * 128;

    const int wR   = wave * 32;
    const int sRow = lane >> 2;
    const int sCol = (((lane & 3) ^ ((sRow >> 1) & 3))) << 3;

    const int lo = lane & 15, quad = lane >> 4;
    const int oq = (wave >> 1) * 64, mq = (wave & 1) * 64;
    const int rdC = (quad ^ ((lo >> 1) & 3)) << 3;

    floatx4 acc[4][4];   // [i = m-frag][j = o-frag]
    #pragma unroll
    for (int i = 0; i < 4; ++i)
        #pragma unroll
        for (int j = 0; j < 4; ++j) acc[i][j] = (floatx4)0.0f;

    for (int kt = 0; kt < 12; ++kt) {
        __syncthreads();
        const int kb = kt * 32;
        #pragma unroll
        for (int u = 0; u < 2; ++u) {
            const int R = wR + u * 16;
            const size_t ga = (size_t)(o0 + R + sRow) * C_DIM + kb + sCol;
            const size_t gb = (size_t)(m0 + R + sRow) * C_DIM + kb + sCol;
            gl_lds16(A0 + ga, &As0[R * 32]);
            gl_lds16(A1 + ga, &As1[R * 32]);
            gl_lds16(B0 + gb, &Bs0[R * 32]);
            gl_lds16(B1 + gb, &Bs1[R * 32]);
        }
        __syncthreads();

        half8 w0F[4], w1F[4], x0F[4], x1F[4];
        #pragma unroll
        for (int j = 0; j < 4; ++j) {
            const int ra = (oq + j * 16 + lo) * 32 + rdC;
            w0F[j] = *(const half8*)&As0[ra];
            w1F[j] = *(const half8*)&As1[ra];
        }
        #pragma unroll
        for (int i = 0; i < 4; ++i) {
            const int rb = (mq + i * 16 + lo) * 32 + rdC;
            x0F[i] = *(const half8*)&Bs0[rb];
            x1F[i] = *(const half8*)&Bs1[rb];
        }
        #pragma unroll
        for (int i = 0; i < 4; ++i) {
            const half8 xS = x0F[i] * (_Float16)4096.0f;   // exact pow2 scale
            #pragma unroll
            for (int j = 0; j < 4; ++j) {
                acc[i][j] = __builtin_amdgcn_mfma_f32_16x16x32_f16(
                    x0F[i], w1F[j], acc[i][j], 0, 0, 0);
                acc[i][j] = __builtin_amdgcn_mfma_f32_16x16x32_f16(
                    x1F[i], w0F[j], acc[i][j], 0, 0, 0);
                acc[i][j] = __builtin_amdgcn_mfma_f32_16x16x32_f16(
                    xS,     w0F[j], acc[i][j], 0, 0, 0);
            }
        }
    }

    // epilogue: D rows = m' (quad picks bs, reg picks t), cols = o.
    #pragma unroll
    for (int j = 0; j < 4; ++j) {
        const int o = o0 + oq + j * 16 + lo;
        const float2 is = invsh[o];
        const float inv = is.x * (1.0f / 4096.0f);
        const float sh  = is.y;
        unsigned char* base = (o < 384) ? spkQ : spkK;
        const int orow = (o < 384) ? o : o - 384;
        #pragma unroll
        for (int i = 0; i < 4; ++i) {
            const int bs = ((m0 + mq + i * 16) >> 2) + quad;
            float v = 0.0f; int bits = 0;
            #pragma unroll
            for (int r = 0; r < 4; ++r) {
                const float xv = acc[i][j][r] * inv + sh;
                const float h = v + (xv - v) * 0.5f;
                const int sp = (h >= 1.0f);
                v = sp ? 0.0f : h;
                bits |= sp << r;
            }
            base[(size_t)bs * C_DIM + orow] = (unsigned char)bits;
        }
    }
}

// ---------------------------------------------------------------------------
// Fused-split proj GEMM, 128m x 64o tile for occupancy (grid 196x6 = 1176
// blocks, 4 blocks/CU): per-block attn recompute, Y built in-register,
// acc += Y*W1 + Y*(4096*W0). Epilogue: in-lane LIF -> per-t LDS transpose
// -> coalesced float4 stores.
// ---------------------------------------------------------------------------
__global__ __launch_bounds__(256, 4)
void proj_mfma(const _Float16* __restrict__ A0, const _Float16* __restrict__ A1,
               const unsigned char* __restrict__ spkQ,
               const unsigned char* __restrict__ spkK,
               const float* __restrict__ bias, const float2* __restrict__ invsh,
               float* __restrict__ out)
{
    __shared__ __align__(16) _Float16 smem[8192];   // 16 KB
    __shared__ unsigned char attnL[256];            // 32 bs x 8 heads
    _Float16* As0 = smem;                 // W0: 64 o-rows x 32
    _Float16* As1 = smem + 2048;          // W1: 64 o-rows x 32
    _Float16* Bs0 = smem + 4096;          // Y : 128 m'-rows x 32

    const int t    = threadIdx.x;
    const int wave = t >> 6, lane = t & 63;
    const int m0 = blockIdx.x * 128;
    const int o0 = blockIdx.y * 64;

    const int wR   = wave * 32;
    const int sRow = lane >> 2;
    const int sCol = (((lane & 3) ^ ((sRow >> 1) & 3))) << 3;   // glds swizzle
    const int gC8  = (lane & 3) << 3;                            // B global chunk
    const int pC8  = sCol;                                       // B LDS swizzle

    const int lo = lane & 15, quad = lane >> 4;
    const int oq = (wave >> 1) * 32, mq = (wave & 1) * 64;
    const int rdC = (quad ^ ((lo >> 1) & 3)) << 3;

    const int bs0g   = m0 >> 2;
    const int bsl[2] = { (wR +  0 + sRow) >> 2, (wR + 16 + sRow) >> 2 }; // local
    const int ttL    = (wR + sRow) & 3;

    // --- per-block attn recompute (exact dyadic) ---
    {
        const int bsl_a = t >> 3, head = t & 7;
        const unsigned long long* p = (const unsigned long long*)
            (spkQ + (size_t)(bs0g + bsl_a) * C_DIM + head * 48);
        int qs[4] = {0, 0, 0, 0};
        #pragma unroll
        for (int u = 0; u < 6; ++u) {
            const unsigned long long v = p[u];
            qs[0] += __popcll(v & 0x0101010101010101ull);
            qs[1] += __popcll(v & 0x0202020202020202ull);
            qs[2] += __popcll(v & 0x0404040404040404ull);
            qs[3] += __popcll(v & 0x0808080808080808ull);
        }
        float va = 0.0f; int bits = 0;
        #pragma unroll
        for (int tt = 0; tt < 4; ++tt) {
            const float h = va + ((float)qs[tt] - va) * 0.5f;
            const int a = (h >= 0.5f);
            va = a ? 0.0f : h;
            bits |= a << tt;
        }
        attnL[t] = (unsigned char)bits;
    }
    __syncthreads();

    floatx4 acc[4][2];   // [i = m-frag][j = o-frag]
    #pragma unroll
    for (int i = 0; i < 4; ++i)
        #pragma unroll
        for (int j = 0; j < 2; ++j) acc[i][j] = (floatx4)0.0f;

    unsigned long long rk[2];
    int rab[2];
    {
        const int head0 = gC8 / 48;
        #pragma unroll
        for (int u = 0; u < 2; ++u) {
            rk[u]  = *(const unsigned long long*)
                     (spkK + (size_t)(bs0g + bsl[u]) * C_DIM + gC8);
            rab[u] = (attnL[bsl[u] * 8 + head0] >> ttL) & 1;
        }
    }

    for (int kt = 0; kt < 12; ++kt) {
        __syncthreads();
        const int kb = kt * 32;
        // A staging: wave w stages W0/W1 rows [w*16, w*16+16) (64 rows total)
        {
            const int R = wave * 16;
            const size_t ga = (size_t)(o0 + R + sRow) * C_DIM + kb + sCol;
            gl_lds16(A0 + ga, &As0[R * 32]);
            gl_lds16(A1 + ga, &As1[R * 32]);
        }
        // B build: wave w writes Y rows [w*32, w*32+32)
        #pragma unroll
        for (int u = 0; u < 2; ++u) {
            const int R = wR + u * 16;
            half8 bv;
            #pragma unroll
            for (int e = 0; e < 8; ++e)
                bv[e] = (_Float16)(float)((int)(rk[u] >> (8 * e + ttL)) & rab[u] & 1);
            *(half8*)&Bs0[(R + sRow) * 32 + pC8] = bv;
        }
        if (kt < 11) {
            const int kb2  = (kt + 1) * 32;
            const int head = (kb2 + gC8) / 48;
            #pragma unroll
            for (int u = 0; u < 2; ++u) {
                rk[u]  = *(const unsigned long long*)
                         (spkK + (size_t)(bs0g + bsl[u]) * C_DIM + kb2 + gC8);
                rab[u] = (attnL[bsl[u] * 8 + head] >> ttL) & 1;
            }
        }
        __syncthreads();

        half8 w0F[2], w1F[2], yF[4];
        #pragma unroll
        for (int j = 0; j < 2; ++j) {
            const int ra = (oq + j * 16 + lo) * 32 + rdC;
            w0F[j] = *(const half8*)&As0[ra];
            w1F[j] = *(const half8*)&As1[ra];
        }
        #pragma unroll
        for (int i = 0; i < 4; ++i)
            yF[i] = *(const half8*)&Bs0[(mq + i * 16 + lo) * 32 + rdC];

        #pragma unroll
        for (int j = 0; j < 2; ++j) {
            const half8 wS = w0F[j] * (_Float16)4096.0f;
            #pragma unroll
            for (int i = 0; i < 4; ++i) {
                acc[i][j] = __builtin_amdgcn_mfma_f32_16x16x32_f16(
                    yF[i], w1F[j], acc[i][j], 0, 0, 0);
                acc[i][j] = __builtin_amdgcn_mfma_f32_16x16x32_f16(
                    yF[i], wS,     acc[i][j], 0, 0, 0);
            }
        }
    }

    // in-lane LIF -> 4 spike bits per (i,j)
    int bits[4][2];
    #pragma unroll
    for (int j = 0; j < 2; ++j) {
        const int o = o0 + oq + j * 16 + lo;
        const float2 is = invsh[o];
        const float bv = bias[o];
        #pragma unroll
        for (int i = 0; i < 4; ++i) {
            float v = 0.0f; int bt = 0;
            #pragma unroll
            for (int r = 0; r < 4; ++r) {
                const float p = acc[i][j][r] * (1.0f / 4096.0f);
                const float z = (p + bv) * is.x + is.y;
                const float h = v + (z - v) * 0.5f;
                const int sp = (h >= 1.0f);
                v = sp ? 0.0f : h;
                bt |= sp << r;
            }
            bits[i][j] = bt;
        }
    }

    // per-t: LDS transpose (64 o x 32 bs, pad 33) + coalesced float4 stores
    float* tile = (float*)smem;            // 64*33*4 B = 8.4 KB
    for (int r = 0; r < 4; ++r) {
        __syncthreads();
        #pragma unroll
        for (int j = 0; j < 2; ++j)
            #pragma unroll
            for (int i = 0; i < 4; ++i)
                tile[(oq + j * 16 + lo) * 33 + (mq >> 2) + i * 4 + quad] =
                    ((bits[i][j] >> r) & 1) ? 1.0f : 0.0f;
        __syncthreads();
        #pragma unroll
        for (int it = 0; it < 2; ++it) {
            const int idx = it * 256 + t;        // 0..511
            const int o   = idx >> 3;            // 0..63
            const int ch  = idx & 7;
            const int bsg = bs0g + ch * 4;       // 4-chunk never straddles b
            const int b   = bsg / S_DIM;
            const int s   = bsg - b * S_DIM;
            float4 vv;
            vv.x = tile[o * 33 + ch * 4 + 0];
            vv.y = tile[o * 33 + ch * 4 + 1];
            vv.z = tile[o * 33 + ch * 4 + 2];
            vv.w = tile[o * 33 + ch * 4 + 3];
            *(float4*)(out + (size_t)r * BCS + (size_t)b * CS_
                           + (size_t)(o0 + o) * S_DIM + s) = vv;
        }
    }
}

// ---------------------------------------------------------------------------
extern "C" void kernel_launch(void* const* d_in, const int* in_sizes, int n_in,
                              void* d_out, int out_size, void* d_ws, size_t ws_size,
                              hipStream_t stream)
{
    const float* x          = (const float*)d_in[0];
    const float* q_w        = (const float*)d_in[1];
    const float* q_gamma    = (const float*)d_in[2];
    const float* q_beta     = (const float*)d_in[3];
    const float* q_mean     = (const float*)d_in[4];
    const float* q_var      = (const float*)d_in[5];
    const float* k_w        = (const float*)d_in[6];
    const float* k_gamma    = (const float*)d_in[7];
    const float* k_beta     = (const float*)d_in[8];
    const float* k_mean     = (const float*)d_in[9];
    const float* k_var      = (const float*)d_in[10];
    const float* proj_w     = (const float*)d_in[11];
    const float* proj_b     = (const float*)d_in[12];
    const float* proj_gamma = (const float*)d_in[13];
    const float* proj_beta  = (const float*)d_in[14];
    const float* proj_mean  = (const float*)d_in[15];
    const float* proj_var   = (const float*)d_in[16];
    float* out = (float*)d_out;

    _Float16* h0 = (_Float16*)d_ws;         // X0 (b,s,t)-major
    _Float16* h1 = h0 + NELEM;              // X1
    _Float16* Wq0 = h1 + NELEM;             // 768x384
    _Float16* Wq1 = Wq0 + 768 * C_DIM;
    _Float16* Wp0 = Wq1 + 768 * C_DIM;      // 384x384
    _Float16* Wp1 = Wp0 + C_DIM * C_DIM;
    float2*   invshQ = (float2*)(Wp1 + C_DIM * C_DIM);   // 768 (q|k)
    float2*   invshP = invshQ + 768;                     // 384 (proj)
    unsigned char* spkQ  = (unsigned char*)(invshP + 384);  // NBS*384
    unsigned char* spkK  = spkQ + (size_t)NBS * C_DIM;

    prep<<<2496, 256, 0, stream>>>(x, q_w, k_w, proj_w,
                                   q_gamma, q_beta, q_mean, q_var,
                                   k_gamma, k_beta, k_mean, k_var,
                                   proj_gamma, proj_beta, proj_mean, proj_var,
                                   h0, h1, Wq0, Wq1, Wp0, Wp1, invshQ, invshP);

    qk_mfma<<<dim3(196, 6), 256, 0, stream>>>(Wq0, Wq1, h0, h1, invshQ,
                                              spkQ, spkK);
    proj_mfma<<<dim3(196, 6), 256, 0, stream>>>(Wp0, Wp1, spkQ, spkK,
                                                proj_b, invshP, out);
}